// Round 1
// 164.558 us; speedup vs baseline: 1.1626x; 1.1626x over previous
//
#include <hip/hip_runtime.h>
#include <math.h>

#define B 2
#define C 32
#define H 128
#define W 416
#define D 48
#define HW (H*W)
#define CHW (C*HW)
#define EPSN 1e-3f
#define ISCALE 0.05892556509887896f   // 1/sqrt(C*9)
#define LSTR 36                        // LDS column stride (floats): 16B-aligned
#define DSPL (D / 2)                   // disparities per block (d-split)

__device__ __forceinline__ float clip10(float x) {
    return fminf(fmaxf(x, -10.0f), 10.0f);
}

// ---------------------------------------------------------------------------
// k_norm: 3x3 zero-padded box of sql/sqr -> inverse patch norms inl/inr.
__global__ __launch_bounds__(256) void k_norm(const float* __restrict__ sql,
                                              const float* __restrict__ sqr,
                                              float* __restrict__ inl,
                                              float* __restrict__ inr) {
    int idx = blockIdx.x * 256 + threadIdx.x;
    if (idx >= B * HW) return;
    int b = idx / HW, hw = idx - b * HW;
    int h = hw / W, w = hw - h * W;
    float sl = 0.f, sr = 0.f;
#pragma unroll
    for (int di = -1; di <= 1; ++di) {
        int hh = h + di;
        if (hh < 0 || hh >= H) continue;
#pragma unroll
        for (int dj = -1; dj <= 1; ++dj) {
            int ww = w + dj;
            if (ww < 0 || ww >= W) continue;
            int p = b * HW + hh * W + ww;
            sl += sql[p];
            sr += sqr[p];
        }
    }
    inl[idx] = 1.0f / fmaxf(sqrtf(sl), EPSN);
    inr[idx] = 1.0f / fmaxf(sqrtf(sr), EPSN);
}

// ---------------------------------------------------------------------------
// stage_row_v2: stage [C][W] row into LDS transposed [w][c], stride LSTR.
// Lane mapping t = [g | cl(3b) | rw(3b)]: 8 w-quads x 8 channels per wave
// -> write banks (16*(rw&1) + 4k + cl)%32 = 16 banks, 4-way. Global side:
// 8 x 128B segments per wave.
__device__ __forceinline__ void stage_row_v2(const float* __restrict__ gsrc,
                                             float* __restrict__ lds,
                                             int tid, int nthreads) {
    for (int t = tid; t < (W / 4) * C; t += nthreads) {
        int rw = t & 7;
        int cl = (t >> 3) & 7;
        int g  = t >> 6;              // 0..51
        int wg = g % 13;
        int ch = g / 13;              // 0..3
        int c  = ch * 8 + cl;
        int w4 = (wg * 8 + rw) * 4;
        float4 v = *(const float4*)(gsrc + (size_t)c * HW + w4);
        lds[(w4 + 0) * LSTR + c] = v.x;
        lds[(w4 + 1) * LSTR + c] = v.y;
        lds[(w4 + 2) * LSTR + c] = v.z;
        lds[(w4 + 3) * LSTR + c] = v.w;
    }
}

// stage_row3_v2: same LDS layout, but stages the VERTICAL 3-tap
// vsum[c,w] = x[c,h-1,w] + x[c,h,w] + x[c,h+1,w] (zero-padded in h).
// Rows are re-read by 3 adjacent h-blocks -> L2/L3 resident.
__device__ __forceinline__ void stage_row3_v2(const float* __restrict__ gsrc,
                                              float* __restrict__ lds,
                                              int h, int tid, int nthreads) {
    for (int t = tid; t < (W / 4) * C; t += nthreads) {
        int rw = t & 7;
        int cl = (t >> 3) & 7;
        int g  = t >> 6;
        int wg = g % 13;
        int ch = g / 13;
        int c  = ch * 8 + cl;
        int w4 = (wg * 8 + rw) * 4;
        const float* p = gsrc + (size_t)c * HW + w4;
        float4 v = *(const float4*)(p);
        if (h > 0) {
            float4 a = *(const float4*)(p - W);
            v.x += a.x; v.y += a.y; v.z += a.z; v.w += a.w;
        }
        if (h < H - 1) {
            float4 a = *(const float4*)(p + W);
            v.x += a.x; v.y += a.y; v.z += a.z; v.w += a.w;
        }
        lds[(w4 + 0) * LSTR + c] = v.x;
        lds[(w4 + 1) * LSTR + c] = v.y;
        lds[(w4 + 2) * LSTR + c] = v.z;
        lds[(w4 + 3) * LSTR + c] = v.w;
    }
}

__device__ __forceinline__ float dot32(const float* __restrict__ fl,
                                       const float* __restrict__ col) {
    const float4* c4 = (const float4*)col;   // 16B-aligned (LSTR*4 = 144)
    float a = 0.0f;
#pragma unroll
    for (int q = 0; q < 8; ++q) {
        float4 v = c4[q];
        a += fl[4 * q + 0] * v.x + fl[4 * q + 1] * v.y
           + fl[4 * q + 2] * v.z + fl[4 * q + 3] * v.w;
    }
    return a;
}

// one column read -> two dots (w and w+1 fragments)
__device__ __forceinline__ void dot32x2(const float* __restrict__ fl0,
                                        const float* __restrict__ fl1,
                                        const float* __restrict__ col,
                                        float& a0, float& a1) {
    const float4* c4 = (const float4*)col;
    float s0 = 0.f, s1 = 0.f;
#pragma unroll
    for (int q = 0; q < 8; ++q) {
        float4 v = c4[q];
        s0 += fl0[4 * q + 0] * v.x + fl0[4 * q + 1] * v.y
            + fl0[4 * q + 2] * v.z + fl0[4 * q + 3] * v.w;
        s1 += fl1[4 * q + 0] * v.x + fl1[4 * q + 1] * v.y
            + fl1[4 * q + 2] * v.z + fl1[4 * q + 3] * v.w;
    }
    a0 = s0; a1 = s1;
}

// ---------------------------------------------------------------------------
// k_lr: sL and sR without precomputed box sums. Stages vsum (vertical 3-tap)
// of the raw input row; the horizontal 3-tap is a rolling sum of consecutive
// column dots g(v): dot(fl, box3x3(x)[:,m]) = g(m-1)+g(m)+g(m+1).
// inm computed inline from the xm values already in registers.
// One block per (b,h,dc). Thread owns (w,w+1): one LDS column read feeds two
// dots; paired float2 stores.
__global__ __launch_bounds__(256) void k_lr(const float* __restrict__ xm,
                                            const float* __restrict__ xl,
                                            const float* __restrict__ xr,
                                            const float* __restrict__ inl,
                                            const float* __restrict__ inr,
                                            float* __restrict__ out) {
    __shared__ float sB[W * LSTR];    // 59904 B
    __shared__ float sIn[W];
    int tid = threadIdx.x;
    int h = blockIdx.x;
    int b = blockIdx.y;
    int d0 = blockIdx.z * DSPL;
    bool act = tid < (W / 2);         // 208 pairs
    int w = 2 * tid;
    int bhw = b * HW + h * W;
    const float* pm = xm + (size_t)b * CHW + h * W;

    float fl0[C], fl1[C];
    if (act) {
        float am0 = 0.f, am1 = 0.f;
#pragma unroll
        for (int c = 0; c < C; ++c) {
            float2 mv = *(const float2*)(pm + c * HW + w);
            fl0[c] = mv.x; fl1[c] = mv.y;
            am0 += mv.x * mv.x; am1 += mv.y * mv.y;
        }
        float im0 = 1.0f / fmaxf(sqrtf(am0), EPSN);
        float im1 = 1.0f / fmaxf(sqrtf(am1), EPSN);
#pragma unroll
        for (int c = 0; c < C; ++c) { fl0[c] *= im0; fl1[c] *= im1; }
    } else {
#pragma unroll
        for (int c = 0; c < C; ++c) { fl0[c] = 0.f; fl1[c] = 0.f; }
    }

    // ---- phase L: columns v = w+d0-1+j. 3-tap completes at center m = v-1
    // at iter j (>=2): s0 -> (d0+j-2, w), s1 -> (d0+j-3, w+1). Store pairs
    // (s0 from iter j-1, s1 from iter j), both d = d0+j-3, at j>=3.
    stage_row3_v2(xl + (size_t)b * CHW + h * W, sB, h, tid, 256);
    for (int j = tid; j < W; j += 256) sIn[j] = inl[bhw + j];
    __syncthreads();
    if (act) {
        float* o = out + ((size_t)b * 3 + 0) * D * HW + h * W;
        float g0a = 0.f, g0b = 0.f, g1a = 0.f, g1b = 0.f, s0p = 0.f;
#pragma unroll 4
        for (int j = 0; j <= DSPL + 2; ++j) {
            int v = w + d0 - 1 + j;
            float c0 = 0.f, c1 = 0.f;
            if (v >= 0 && v < W) dot32x2(fl0, fl1, sB + v * LSTR, c0, c1);
            float s0 = 0.f, s1 = 0.f;
            if (j >= 2) {
                int m = v - 1;                 // center; m >= 0 guaranteed
                if (m < W) {
                    float sc = sIn[m] * ISCALE;
                    s0 = clip10((g0a + g0b + c0) * sc);
                    s1 = clip10((g1a + g1b + c1) * sc);
                }
                if (j >= 3) {
                    int d = d0 + j - 3;
                    *(float2*)(o + (size_t)d * HW + w) = make_float2(s0p, s1);
                }
            }
            s0p = s0;
            g0a = g0b; g0b = c0;
            g1a = g1b; g1b = c1;
        }
    }
    __syncthreads();

    // ---- phase R: columns v = w-d0-DSPL+j ascending. Center m = v-1 at
    // iter j: s0 -> (d0+DSPL+1-j, w), s1 -> (d0+DSPL+2-j, w+1). Store pairs
    // at j>=3 for d = d0+DSPL+2-j.
    stage_row3_v2(xr + (size_t)b * CHW + h * W, sB, h, tid, 256);
    for (int j = tid; j < W; j += 256) sIn[j] = inr[bhw + j];
    __syncthreads();
    if (act) {
        float* o = out + ((size_t)b * 3 + 1) * D * HW + h * W;
        float g0a = 0.f, g0b = 0.f, g1a = 0.f, g1b = 0.f, s0p = 0.f;
#pragma unroll 4
        for (int j = 0; j <= DSPL + 2; ++j) {
            int v = w - d0 - DSPL + j;
            float c0 = 0.f, c1 = 0.f;
            if (v >= 0 && v < W) dot32x2(fl0, fl1, sB + v * LSTR, c0, c1);
            float s0 = 0.f, s1 = 0.f;
            if (j >= 2) {
                int m = v - 1;                 // center; m < W guaranteed
                if (m >= 0) {
                    float sc = sIn[m] * ISCALE;
                    s0 = clip10((g0a + g0b + c0) * sc);
                    s1 = clip10((g1a + g1b + c1) * sc);
                }
                if (j >= 3) {
                    int d = d0 + DSPL + 2 - j;
                    *(float2*)(o + (size_t)d * HW + w) = make_float2(s0p, s1);
                }
            }
            s0p = s0;
            g0a = g0b; g0b = c0;
            g1a = g1b; g1b = c1;
        }
    }
}

// ---------------------------------------------------------------------------
// k_e: EH[b,d,h,v] = horizontal 3-tap of E, E[v] = sum_c xl[.,v+2d]*xr[.,v].
// Wave-halo: each wave computes e at v = wave*62 + lane - 1, emits 62 sums
// via shuffles. dc splits d in two -> 2 blocks/CU resident.
// dc==0 blocks additionally emit sql/sqr (channel sum-of-squares rows):
// xr column is already in registers, xl column is one LDS read.
__global__ __launch_bounds__(448) void k_e(const float* __restrict__ xl,
                                           const float* __restrict__ xr,
                                           float* __restrict__ EH,
                                           float* __restrict__ sql,
                                           float* __restrict__ sqr) {
    __shared__ float sXL[W * LSTR];   // 59904 B
    int tid = threadIdx.x;
    int h = blockIdx.x;
    int b = blockIdx.y;
    int d0 = blockIdx.z * DSPL;
    int lane = tid & 63;
    int wv = tid >> 6;                // 0..6
    int v = wv * 62 + lane - 1;       // -1 .. 433
    bool vin = (v >= 0) && (v < W);
    const float* br = xr + (size_t)b * CHW + h * W;

    float xrv[C];
#pragma unroll
    for (int c = 0; c < C; ++c) xrv[c] = vin ? br[c * HW + v] : 0.0f;

    stage_row_v2(xl + (size_t)b * CHW + h * W, sXL, tid, 448);
    __syncthreads();

    bool wr = (lane >= 1) && (lane <= 62) && (v < W);   // v>=0 implied

    if (blockIdx.z == 0) {
        float sr_ = 0.f, sl_ = 0.f;
#pragma unroll
        for (int c = 0; c < C; ++c) sr_ += xrv[c] * xrv[c];
        if (vin) {
            const float4* c4 = (const float4*)(sXL + v * LSTR);
#pragma unroll
            for (int q = 0; q < 8; ++q) {
                float4 x = c4[q];
                sl_ += x.x * x.x + x.y * x.y + x.z * x.z + x.w * x.w;
            }
        }
        if (wr) {
            sqr[b * HW + h * W + v] = sr_;
            sql[b * HW + h * W + v] = sl_;
        }
    }

    float* pe = EH + (((size_t)b * D) * H + h) * W + v;
    for (int d = d0; d < d0 + DSPL; ++d) {
        int s = 2 * d;
        float e = 0.0f;
        if (vin && v + s < W) e = dot32(xrv, sXL + (v + s) * LSTR);
        float em = __shfl_up(e, 1);
        float ep = __shfl_down(e, 1);
        float eh = em + e + ep;
        if (wr) pe[(size_t)d * HW] = eh;
    }
}

// ---------------------------------------------------------------------------
// k_lr2: sLR = vertical 3-tap of EH at column vc=w-d, times inverse norms.
#define DCH 12
__global__ __launch_bounds__(448) void k_lr2(const float* __restrict__ EH,
                                             const float* __restrict__ inl,
                                             const float* __restrict__ inr,
                                             float* __restrict__ out) {
    int w = threadIdx.x;
    int dc = blockIdx.x;              // 0..3
    int h = blockIdx.y;
    int b = blockIdx.z;
    if (w >= W) return;
    int bhw = b * HW + h * W;
    bool hm = (h > 0), hp = (h < H - 1);

    float* o = out + ((size_t)b * 3 + 2) * D * HW + h * W + w;
#pragma unroll
    for (int i = 0; i < DCH; ++i) {
        int d = dc * DCH + i;
        float r = 0.0f;
        if (w >= d && w + d < W) {
            int vc = w - d;
            const float* base = EH + ((size_t)b * D + d) * HW + vc;
            float e = base[h * W];
            if (hm) e += base[(h - 1) * W];
            if (hp) e += base[(h + 1) * W];
            float nl = inl[bhw + w + d];
            float nr = inr[bhw + vc];
            r = clip10(e * nl * nr * ISCALE);
        }
        o[(size_t)d * HW] = r;
    }
}

// ---------------------------------------------------------------------------
extern "C" void kernel_launch(void* const* d_in, const int* in_sizes, int n_in,
                              void* d_out, int out_size, void* d_ws, size_t ws_size,
                              hipStream_t stream) {
    const float* xl = (const float*)d_in[0];
    const float* xm = (const float*)d_in[1];
    const float* xr = (const float*)d_in[2];
    float* out = (float*)d_out;

    float* ws = (float*)d_ws;
    float* inl = ws;                               // B*HW
    float* inr = inl + B * HW;                     // B*HW
    float* sql = inr + B * HW;                     // B*HW
    float* sqr = sql + B * HW;                     // B*HW
    float* EH  = sqr + B * HW;                     // B*D*H*W

    k_e<<<dim3(H, B, 2), dim3(448), 0, stream>>>(xl, xr, EH, sql, sqr);
    k_norm<<<dim3((B * HW + 255) / 256), dim3(256), 0, stream>>>(sql, sqr, inl, inr);
    k_lr<<<dim3(H, B, 2), dim3(256), 0, stream>>>(xm, xl, xr, inl, inr, out);
    k_lr2<<<dim3(4, H, B), dim3(448), 0, stream>>>(EH, inl, inr, out);
}